// Round 15
// baseline (167.607 us; speedup 1.0000x reference)
//
#include <hip/hip_runtime.h>
#include <cstdint>
#include <cstddef>

// Problem constants (from reference): B=2048, IN=4, H=1024, L=4, OUT=256
#define Bsz   2048
#define INsz  4
#define Hsz   1024
#define Lsz   4
#define OUTsz 256

// ============================================================================
// ANCHOR: R14 passed (167.5 µs, absmax 2.93e-3). gru_fused staging/sync/
// fragment machinery FROZEN (5 structural redesigns -> 5 deterministic
// failures, R5-R8+R10). R15 change (epilogue-only, bounded numerics): the
// GRU blend term now uses the bf16 hidden (`hb`, already a kernel arg and
// L2-warm from phase-1 staging) instead of a separate fp32 `hold` stream.
// |bf16(h)-h| <= 1e-4 for h in [-0.05,0.05]; per-layer, non-compounding.
// Saves 8 MB HBM fetch per layer. No other changes.
// ============================================================================

typedef float f32x4 __attribute__((ext_vector_type(4)));
typedef short s16x8 __attribute__((ext_vector_type(8)));

typedef __attribute__((address_space(1))) void gvoid_t;  // global
typedef __attribute__((address_space(3))) void svoid_t;  // LDS

__device__ __forceinline__ unsigned short f2bf(float f) {
    union { float f; unsigned int u; } v; v.f = f;
    unsigned int r = 0x7FFFu + ((v.u >> 16) & 1u);
    return (unsigned short)((v.u + r) >> 16);
}

__device__ __forceinline__ float bf2f(unsigned short s) {
    union { unsigned int u; float f; } v;
    v.u = ((unsigned int)s) << 16;
    return v.f;
}

__device__ __forceinline__ float sigm(float x) {
    return 1.0f / (1.0f + __expf(-x));
}
__device__ __forceinline__ float tanh_fast(float x) {
    float a = __expf(-2.0f * fabsf(x));
    float t = (1.0f - a) / (1.0f + a);
    return copysignf(t, x);
}

// Inline-asm MFMA: signature-proof vs builtin bf16/short ambiguity.
__device__ __forceinline__ void mfma_bf16(f32x4& c, s16x8 a, s16x8 b) {
    asm("v_mfma_f32_16x16x32_bf16 %0, %1, %2, %0" : "+v"(c) : "v"(a), "v"(b));
}

// ---------------- pre-work bodies (arithmetic identical to proven kernels) ----------------
__device__ __forceinline__ void body_cast8(const float* __restrict__ in,
                                           unsigned short* __restrict__ out, int i) {
    const float4* p = (const float4*)in;
    float4 a = p[2 * i], b = p[2 * i + 1];
    union { unsigned short s[8]; uint4 u; } o;
    o.s[0] = f2bf(a.x); o.s[1] = f2bf(a.y); o.s[2] = f2bf(a.z); o.s[3] = f2bf(a.w);
    o.s[4] = f2bf(b.x); o.s[5] = f2bf(b.y); o.s[6] = f2bf(b.z); o.s[7] = f2bf(b.w);
    ((uint4*)out)[i] = o.u;
}

// weight gate-group reorder: out row' = l*3H + (j>>4)*48 + gate*16 + (j&15)
__device__ __forceinline__ void body_reorder(const float* __restrict__ in,
                                             unsigned short* __restrict__ out, int i) {
    int k8  = i & (Hsz / 8 - 1);          // 128 chunks per row
    int row = i >> 7;
    int l    = row / (3 * Hsz);
    int lrow = row - l * (3 * Hsz);
    int gate = lrow >> 10;
    int j    = lrow & (Hsz - 1);
    int rowp = l * (3 * Hsz) + ((j >> 4) * 48) + gate * 16 + (j & 15);
    const float4* p = (const float4*)(in + (size_t)row * Hsz + k8 * 8);
    float4 a = p[0], b = p[1];
    union { unsigned short s[8]; uint4 u; } o;
    o.s[0] = f2bf(a.x); o.s[1] = f2bf(a.y); o.s[2] = f2bf(a.z); o.s[3] = f2bf(a.w);
    o.s[4] = f2bf(b.x); o.s[5] = f2bf(b.y); o.s[6] = f2bf(b.z); o.s[7] = f2bf(b.w);
    *(uint4*)(out + (size_t)rowp * Hsz + k8 * 8) = o.u;
}

// i2h, 4 columns per item: same per-element fp32 arithmetic as the proven
// scalar body (dot(xi,wj) + b[j]), vectorized store (ushort4).
__device__ __forceinline__ void body_i2h4(const float* __restrict__ inp,
                                          const float* __restrict__ w,
                                          const float* __restrict__ b,
                                          unsigned short* __restrict__ xb, int idx) {
    int m  = idx >> 8;               // batch row (256 items of 4 cols per row)
    int j0 = (idx & 255) << 2;       // first of 4 columns
    float4 xi = ((const float4*)inp)[m];
    float4 bv = *(const float4*)(b + j0);
    ushort4 o;
    {
        float4 wj = ((const float4*)w)[j0 + 0];
        o.x = f2bf(xi.x * wj.x + xi.y * wj.y + xi.z * wj.z + xi.w * wj.w + bv.x);
    }
    {
        float4 wj = ((const float4*)w)[j0 + 1];
        o.y = f2bf(xi.x * wj.x + xi.y * wj.y + xi.z * wj.z + xi.w * wj.w + bv.y);
    }
    {
        float4 wj = ((const float4*)w)[j0 + 2];
        o.z = f2bf(xi.x * wj.x + xi.y * wj.y + xi.z * wj.z + xi.w * wj.w + bv.z);
    }
    {
        float4 wj = ((const float4*)w)[j0 + 3];
        o.w = f2bf(xi.x * wj.x + xi.y * wj.y + xi.z * wj.z + xi.w * wj.w + bv.w);
    }
    *(ushort4*)(xb + (size_t)m * Hsz + j0) = o;
}

// ---------------- ONE grid-stride pre-work launch (G11 form) ----------------
#define PW_N1 1572864
#define PW_N2 3145728
#define PW_N3 3178496
#define PW_N4 4227072
#define PW_TOT 4751360
__global__ void prework(const float* __restrict__ w_ih, unsigned short* __restrict__ wih16,
                        const float* __restrict__ w_hh, unsigned short* __restrict__ whh16,
                        const float* __restrict__ dec_w, unsigned short* __restrict__ wdec16,
                        const float* __restrict__ hidden, unsigned short* __restrict__ h16,
                        const float* __restrict__ input, const float* __restrict__ i2h_w,
                        const float* __restrict__ i2h_b, unsigned short* __restrict__ xb0) {
    const int stride = gridDim.x * blockDim.x;
    for (int t = blockIdx.x * blockDim.x + threadIdx.x; t < PW_TOT; t += stride) {
        if (t < PW_N1)      body_reorder(w_ih, wih16, t);
        else if (t < PW_N2) body_reorder(w_hh, whh16, t - PW_N1);
        else if (t < PW_N3) body_cast8(dec_w, wdec16, t - PW_N2);
        else if (t < PW_N4) body_cast8(hidden, h16, t - PW_N3);
        else                body_i2h4(input, i2h_w, i2h_b, xb0, t - PW_N4);
    }
}

// ---------------- Fused GRU layer: concat-K dual GEMM + gate math ----------------
// FROZEN structure from R11/R14 (passing). Concat-K over K=2048 (tiles 0..15:
// A=x,B=Wi; 16..31: A=h,B=Wh); r,z accumulate the sum; n-gate keeps i_n / h_n
// separate. Tile 128 rows x 32 gate-cols (96 reordered W rows), 4 waves (2x2).
// STAGE(t+1) ahead + one __syncthreads per tile; LDS dbuf 2x28KB, 2 blk/CU.
// L2-residency swizzle: per XCD 4 colTiles x 16 rowTiles (W set 768KB).
// R15: blend term reads bf16 hidden (hb) instead of a separate fp32 stream.
#define BUFSZ (224 * 64)   // (128 A-rows + 96 B-rows) * 64 k, elements
__global__ __launch_bounds__(256, 2)
void gru_fused(const unsigned short* __restrict__ x,   // [B,H] bf16 layer input
               const unsigned short* __restrict__ hb,  // [B,H] bf16 h_{t-1}
               const unsigned short* __restrict__ Wi,  // [3H,H] bf16 reordered
               const unsigned short* __restrict__ Wh,  // [3H,H] bf16 reordered
               const float* __restrict__ bih,          // [3H] original layout
               const float* __restrict__ bhh,          // [3H] original layout
               float* __restrict__ hout,               // [B,H] fp32 h'
               unsigned short* __restrict__ xout) {    // [B,H] bf16 h'
    const int bid = blockIdx.x;
    const int ii  = bid >> 3;               // 0..63 within XCD
    const int my  = ii & 15;                // row tile 0..15
    const int nxi = (bid & 7) * 4 + (ii >> 4);  // col tile 0..31

    __shared__ __align__(16) unsigned short lds[2 * BUFSZ];

    const int tid  = threadIdx.x;
    const int lane = tid & 63;
    const int w    = tid >> 6;
    const int wr   = w >> 1;         // wave row (0..1)
    const int wc   = w & 1;          // wave col / 16-col group (0..1)
    const long rowBase = (long)my * 128;
    const long colW    = (long)nxi * 96;   // reordered W row base

    f32x4 rz[4][2] = {};   // r,z gate sums (i+h), accumulated over all 32 steps
    f32x4 nin[4] = {};     // i_n (phase 0)
    f32x4 nhn[4] = {};     // h_n (phase 1)

    // ---- hoisted loop-invariant STAGE geometry (identical address values) ----
    long aoffE[4];                   // A-tile: global element offset per chunk i
    int  acb[4];                     // A-tile: LDS chunk base per i
    #pragma unroll
    for (int i = 0; i < 4; ++i) {
        const int cbase = (w * 4 + i) * 64;
        const int c = cbase + lane;
        const int r = c >> 3, jc = c & 7;
        const int js = (jc ^ (r & 7)) << 3;
        aoffE[i] = (rowBase + r) * (long)Hsz + js;
        acb[i]   = cbase;
    }
    long boffE[3];                   // B-tile
    int  bcb[3];
    #pragma unroll
    for (int i = 0; i < 3; ++i) {
        const int cbase = (w * 3 + i) * 64;
        const int c = cbase + lane;
        const int r = c >> 3, jc = c & 7;
        const int js = (jc ^ (r & 7)) << 3;
        boffE[i] = (colW + r) * (long)Hsz + js;
        bcb[i]   = cbase;
    }

    // Issue the 7 global_load_lds for K-tile tn into buffer buf.
    auto STAGE = [&](int tn, int buf) {
        const unsigned short* Ap = (tn < 16) ? x : hb;
        const unsigned short* Wp = (tn < 16) ? Wi : Wh;
        const long koff = (long)(tn & 15) * 64;
        unsigned short* la = lds + buf * BUFSZ;
        unsigned short* lb = la + 128 * 64;
        #pragma unroll
        for (int i = 0; i < 4; ++i)
            __builtin_amdgcn_global_load_lds((gvoid_t*)(Ap + aoffE[i] + koff),
                                             (svoid_t*)(la + acb[i] * 8), 16, 0, 0);
        #pragma unroll
        for (int i = 0; i < 3; ++i)
            __builtin_amdgcn_global_load_lds((gvoid_t*)(Wp + boffE[i] + koff),
                                             (svoid_t*)(lb + bcb[i] * 8), 16, 0, 0);
    };

    auto COMPUTE = [&](int t) {
        const unsigned short* la = lds + (t & 1) * BUFSZ;
        const unsigned short* lb = la + 128 * 64;
        const bool ph0 = (t < 16);               // wave-uniform
        #pragma unroll
        for (int kk = 0; kk < 2; ++kk) {
            s16x8 av[4], bv[3];
            const int jk = kk * 4 + (lane >> 4);
            #pragma unroll
            for (int mi = 0; mi < 4; ++mi) {
                int r = wr * 64 + mi * 16 + (lane & 15);
                av[mi] = *(const s16x8*)&la[r * 64 + ((jk ^ (r & 7)) << 3)];
            }
            #pragma unroll
            for (int ni = 0; ni < 3; ++ni) {
                int r = wc * 48 + ni * 16 + (lane & 15);
                bv[ni] = *(const s16x8*)&lb[r * 64 + ((jk ^ (r & 7)) << 3)];
            }
            __builtin_amdgcn_s_setprio(1);
            #pragma unroll
            for (int mi = 0; mi < 4; ++mi) {
                mfma_bf16(rz[mi][0], av[mi], bv[0]);
                mfma_bf16(rz[mi][1], av[mi], bv[1]);
            }
            if (ph0) {
                #pragma unroll
                for (int mi = 0; mi < 4; ++mi) mfma_bf16(nin[mi], av[mi], bv[2]);
            } else {
                #pragma unroll
                for (int mi = 0; mi < 4; ++mi) mfma_bf16(nhn[mi], av[mi], bv[2]);
            }
            __builtin_amdgcn_s_setprio(0);
        }
    };

    STAGE(0, 0);
    __syncthreads();                  // vmcnt(0) drain + barrier: tile 0 ready
    #pragma unroll
    for (int t = 0; t < 31; ++t) {
        STAGE(t + 1, (t + 1) & 1);    // overlaps with COMPUTE(t)
        COMPUTE(t);
        __syncthreads();              // drains t+1 loads; protects buf reuse
    }
    COMPUTE(31);

    // Guard MFMA-write -> VALU-read hazard (inline-asm MFMA bypasses the
    // compiler's hazard recognizer).
    asm volatile("s_nop 7\n\ts_nop 7");

    // ---- GRU epilogue (all per-lane, no cross-lane) ----
    const int j = nxi * 32 + wc * 16 + (lane & 15);   // gate column 0..1023
    const float br = bih[j]           + bhh[j];
    const float bz = bih[Hsz + j]     + bhh[Hsz + j];
    const float bin = bih[2 * Hsz + j];
    const float bhn = bhh[2 * Hsz + j];

    #pragma unroll
    for (int mi = 0; mi < 4; ++mi) {
        #pragma unroll
        for (int q = 0; q < 4; ++q) {
            long row = rowBase + wr * 64 + mi * 16 + ((lane >> 4) << 2) + q;
            float r = sigm(rz[mi][0][q] + br);
            float z = sigm(rz[mi][1][q] + bz);
            float n = tanh_fast(nin[mi][q] + bin + r * (nhn[mi][q] + bhn));
            float hv = bf2f(hb[row * Hsz + j]);   // bf16 hidden (L2-warm)
            float o  = (1.0f - z) * n + z * hv;
            hout[row * Hsz + j] = o;
            xout[row * Hsz + j] = f2bf(o);
        }
    }
}

// ---------------- decoder GEMM: C = A @ W^T + b (128x128 tile, m97 structure) ----------------
__global__ __launch_bounds__(256)
void gemm_dec(const unsigned short* __restrict__ A, const unsigned short* __restrict__ Bw,
              const float* __restrict__ bias, float* __restrict__ C,
              int M, int N, int K, int nx) {
    const int nwg = gridDim.x;
    const int cpx = nwg >> 3;
    const int bid = blockIdx.x;
    const int swz = (bid & 7) * cpx + (bid >> 3);
    const int my  = swz / nx;
    const int nxi = swz - my * nx;

    __shared__ __align__(16) unsigned short lA[128 * 64];
    __shared__ __align__(16) unsigned short lB[128 * 64];

    const int tid  = threadIdx.x;
    const int lane = tid & 63;
    const int w    = tid >> 6;
    const int wr   = w >> 1;
    const int wc   = w & 1;
    const long rowBase = (long)my * 128;
    const long colBase = (long)nxi * 128;

    f32x4 acc[4][4] = {};

    for (int k0 = 0; k0 < K; k0 += 64) {
        __syncthreads();
        #pragma unroll
        for (int i = 0; i < 4; ++i) {
            const int cbase = (w * 4 + i) * 64;
            const int c = cbase + lane;
            const int r = c >> 3, jc = c & 7;
            const int js = (jc ^ (r & 7)) << 3;
            __builtin_amdgcn_global_load_lds((gvoid_t*)(A  + (rowBase + r) * (long)K + k0 + js),
                                             (svoid_t*)(lA + cbase * 8), 16, 0, 0);
            __builtin_amdgcn_global_load_lds((gvoid_t*)(Bw + (colBase + r) * (long)K + k0 + js),
                                             (svoid_t*)(lB + cbase * 8), 16, 0, 0);
        }
        __syncthreads();

        #pragma unroll
        for (int kk = 0; kk < 2; ++kk) {
            s16x8 af[4], bf[4];
            const int jk = kk * 4 + (lane >> 4);
            #pragma unroll
            for (int mi = 0; mi < 4; ++mi) {
                int r = wr * 64 + mi * 16 + (lane & 15);
                af[mi] = *(const s16x8*)&lA[r * 64 + ((jk ^ (r & 7)) << 3)];
            }
            #pragma unroll
            for (int ni = 0; ni < 4; ++ni) {
                int r = wc * 64 + ni * 16 + (lane & 15);
                bf[ni] = *(const s16x8*)&lB[r * 64 + ((jk ^ (r & 7)) << 3)];
            }
            #pragma unroll
            for (int mi = 0; mi < 4; ++mi)
                #pragma unroll
                for (int ni = 0; ni < 4; ++ni)
                    mfma_bf16(acc[mi][ni], af[mi], bf[ni]);
        }
    }

    asm volatile("s_nop 7\n\ts_nop 7");

    #pragma unroll
    for (int mi = 0; mi < 4; ++mi) {
        #pragma unroll
        for (int ni = 0; ni < 4; ++ni) {
            long col = colBase + wc * 64 + ni * 16 + (lane & 15);
            float bv = bias[col];
            #pragma unroll
            for (int q = 0; q < 4; ++q) {
                long row = rowBase + wr * 64 + mi * 16 + (lane >> 4) * 4 + q;
                C[row * (long)N + col] = acc[mi][ni][q] + bv;
            }
        }
    }
}

extern "C" void kernel_launch(void* const* d_in, const int* in_sizes, int n_in,
                              void* d_out, int out_size, void* d_ws, size_t ws_size,
                              hipStream_t stream) {
    const float* input  = (const float*)d_in[0];
    const float* hidden = (const float*)d_in[1];
    const float* i2h_w  = (const float*)d_in[2];
    const float* i2h_b  = (const float*)d_in[3];
    const float* w_ih   = (const float*)d_in[4];
    const float* w_hh   = (const float*)d_in[5];
    const float* b_ih   = (const float*)d_in[6];
    const float* b_hh   = (const float*)d_in[7];
    const float* dec_w  = (const float*)d_in[8];
    const float* dec_b  = (const float*)d_in[9];

    float* logits = (float*)d_out;                       // [B, OUT]
    float* new_h  = (float*)d_out + (size_t)Bsz * OUTsz; // [L, B, H]

    // Workspace layout (~76 MB)
    char* p = (char*)d_ws;
    unsigned short* wih16  = (unsigned short*)p; p += (size_t)Lsz * 3 * Hsz * Hsz * 2;
    unsigned short* whh16  = (unsigned short*)p; p += (size_t)Lsz * 3 * Hsz * Hsz * 2;
    unsigned short* wdec16 = (unsigned short*)p; p += (size_t)OUTsz * Hsz * 2;
    unsigned short* h16    = (unsigned short*)p; p += (size_t)Lsz * Bsz * Hsz * 2;
    unsigned short* xb0    = (unsigned short*)p; p += (size_t)Bsz * Hsz * 2;
    unsigned short* xb1    = (unsigned short*)p; p += (size_t)Bsz * Hsz * 2;
    unsigned short* xbuf[2] = { xb0, xb1 };

    // 1) ALL pre-work in one grid-stride launch (G11: 4096 blocks)
    prework<<<4096, 256, 0, stream>>>(w_ih, wih16, w_hh, whh16,
                                      dec_w, wdec16, hidden, h16,
                                      input, i2h_w, i2h_b, xb0);

    // 2) fused GRU layers (one launch each; structure-frozen kernel)
    for (int l = 0; l < Lsz; ++l) {
        gru_fused<<<512, 256, 0, stream>>>(
            xbuf[l & 1],
            h16 + (size_t)l * Bsz * Hsz,
            wih16 + (size_t)l * 3 * Hsz * Hsz,
            whh16 + (size_t)l * 3 * Hsz * Hsz,
            b_ih + (size_t)l * 3 * Hsz,
            b_hh + (size_t)l * 3 * Hsz,
            new_h + (size_t)l * Bsz * Hsz,
            xbuf[(l + 1) & 1]);
    }

    // 3) decoder: logits = h3 @ dec_w.T + dec_b   (h3 is in xbuf[0] after 4 layers)
    {
        int nx = OUTsz / 128;                          // 2
        int blocks = nx * (Bsz / 128);                 // 32
        gemm_dec<<<blocks, 256, 0, stream>>>(xbuf[Lsz & 1], wdec16, dec_b, logits,
                                             Bsz, OUTsz, Hsz, nx);
    }
}

// Round 16
// 166.577 us; speedup vs baseline: 1.0062x; 1.0062x over previous
//
#include <hip/hip_runtime.h>
#include <cstdint>
#include <cstddef>

// Problem constants (from reference): B=2048, IN=4, H=1024, L=4, OUT=256
#define Bsz   2048
#define INsz  4
#define Hsz   1024
#define Lsz   4
#define OUTsz 256

// ============================================================================
// ANCHOR: R15 passed (167.6 µs, absmax 2.93e-3). gru_fused staging/sync/
// fragment machinery FROZEN (5 structural redesigns -> 5 deterministic
// failures, R5-R8+R10). Model update (R16): per-step LDS traffic 168 KB/CU
// at 128 B/clk ~= the observed step time -> kernel is LDS-BW-bound.
// R16 change: remove the s_setprio(1/0) hint pair around the MFMA cluster
// (pure scheduler hint, zero semantic effect). At LDS-BW-bound lockstep
// schedules setprio is null-to-negative (m190: -14 TF on GEMM; T5 pays only
// on 8-phase role-split schedules). Everything else byte-identical to R15.
// ============================================================================

typedef float f32x4 __attribute__((ext_vector_type(4)));
typedef short s16x8 __attribute__((ext_vector_type(8)));

typedef __attribute__((address_space(1))) void gvoid_t;  // global
typedef __attribute__((address_space(3))) void svoid_t;  // LDS

__device__ __forceinline__ unsigned short f2bf(float f) {
    union { float f; unsigned int u; } v; v.f = f;
    unsigned int r = 0x7FFFu + ((v.u >> 16) & 1u);
    return (unsigned short)((v.u + r) >> 16);
}

__device__ __forceinline__ float bf2f(unsigned short s) {
    union { unsigned int u; float f; } v;
    v.u = ((unsigned int)s) << 16;
    return v.f;
}

__device__ __forceinline__ float sigm(float x) {
    return 1.0f / (1.0f + __expf(-x));
}
__device__ __forceinline__ float tanh_fast(float x) {
    float a = __expf(-2.0f * fabsf(x));
    float t = (1.0f - a) / (1.0f + a);
    return copysignf(t, x);
}

// Inline-asm MFMA: signature-proof vs builtin bf16/short ambiguity.
__device__ __forceinline__ void mfma_bf16(f32x4& c, s16x8 a, s16x8 b) {
    asm("v_mfma_f32_16x16x32_bf16 %0, %1, %2, %0" : "+v"(c) : "v"(a), "v"(b));
}

// ---------------- pre-work bodies (arithmetic identical to proven kernels) ----------------
__device__ __forceinline__ void body_cast8(const float* __restrict__ in,
                                           unsigned short* __restrict__ out, int i) {
    const float4* p = (const float4*)in;
    float4 a = p[2 * i], b = p[2 * i + 1];
    union { unsigned short s[8]; uint4 u; } o;
    o.s[0] = f2bf(a.x); o.s[1] = f2bf(a.y); o.s[2] = f2bf(a.z); o.s[3] = f2bf(a.w);
    o.s[4] = f2bf(b.x); o.s[5] = f2bf(b.y); o.s[6] = f2bf(b.z); o.s[7] = f2bf(b.w);
    ((uint4*)out)[i] = o.u;
}

// weight gate-group reorder: out row' = l*3H + (j>>4)*48 + gate*16 + (j&15)
__device__ __forceinline__ void body_reorder(const float* __restrict__ in,
                                             unsigned short* __restrict__ out, int i) {
    int k8  = i & (Hsz / 8 - 1);          // 128 chunks per row
    int row = i >> 7;
    int l    = row / (3 * Hsz);
    int lrow = row - l * (3 * Hsz);
    int gate = lrow >> 10;
    int j    = lrow & (Hsz - 1);
    int rowp = l * (3 * Hsz) + ((j >> 4) * 48) + gate * 16 + (j & 15);
    const float4* p = (const float4*)(in + (size_t)row * Hsz + k8 * 8);
    float4 a = p[0], b = p[1];
    union { unsigned short s[8]; uint4 u; } o;
    o.s[0] = f2bf(a.x); o.s[1] = f2bf(a.y); o.s[2] = f2bf(a.z); o.s[3] = f2bf(a.w);
    o.s[4] = f2bf(b.x); o.s[5] = f2bf(b.y); o.s[6] = f2bf(b.z); o.s[7] = f2bf(b.w);
    *(uint4*)(out + (size_t)rowp * Hsz + k8 * 8) = o.u;
}

// i2h, 4 columns per item: same per-element fp32 arithmetic as the proven
// scalar body (dot(xi,wj) + b[j]), vectorized store (ushort4).
__device__ __forceinline__ void body_i2h4(const float* __restrict__ inp,
                                          const float* __restrict__ w,
                                          const float* __restrict__ b,
                                          unsigned short* __restrict__ xb, int idx) {
    int m  = idx >> 8;               // batch row (256 items of 4 cols per row)
    int j0 = (idx & 255) << 2;       // first of 4 columns
    float4 xi = ((const float4*)inp)[m];
    float4 bv = *(const float4*)(b + j0);
    ushort4 o;
    {
        float4 wj = ((const float4*)w)[j0 + 0];
        o.x = f2bf(xi.x * wj.x + xi.y * wj.y + xi.z * wj.z + xi.w * wj.w + bv.x);
    }
    {
        float4 wj = ((const float4*)w)[j0 + 1];
        o.y = f2bf(xi.x * wj.x + xi.y * wj.y + xi.z * wj.z + xi.w * wj.w + bv.y);
    }
    {
        float4 wj = ((const float4*)w)[j0 + 2];
        o.z = f2bf(xi.x * wj.x + xi.y * wj.y + xi.z * wj.z + xi.w * wj.w + bv.z);
    }
    {
        float4 wj = ((const float4*)w)[j0 + 3];
        o.w = f2bf(xi.x * wj.x + xi.y * wj.y + xi.z * wj.z + xi.w * wj.w + bv.w);
    }
    *(ushort4*)(xb + (size_t)m * Hsz + j0) = o;
}

// ---------------- ONE grid-stride pre-work launch (G11 form) ----------------
#define PW_N1 1572864
#define PW_N2 3145728
#define PW_N3 3178496
#define PW_N4 4227072
#define PW_TOT 4751360
__global__ void prework(const float* __restrict__ w_ih, unsigned short* __restrict__ wih16,
                        const float* __restrict__ w_hh, unsigned short* __restrict__ whh16,
                        const float* __restrict__ dec_w, unsigned short* __restrict__ wdec16,
                        const float* __restrict__ hidden, unsigned short* __restrict__ h16,
                        const float* __restrict__ input, const float* __restrict__ i2h_w,
                        const float* __restrict__ i2h_b, unsigned short* __restrict__ xb0) {
    const int stride = gridDim.x * blockDim.x;
    for (int t = blockIdx.x * blockDim.x + threadIdx.x; t < PW_TOT; t += stride) {
        if (t < PW_N1)      body_reorder(w_ih, wih16, t);
        else if (t < PW_N2) body_reorder(w_hh, whh16, t - PW_N1);
        else if (t < PW_N3) body_cast8(dec_w, wdec16, t - PW_N2);
        else if (t < PW_N4) body_cast8(hidden, h16, t - PW_N3);
        else                body_i2h4(input, i2h_w, i2h_b, xb0, t - PW_N4);
    }
}

// ---------------- Fused GRU layer: concat-K dual GEMM + gate math ----------------
// FROZEN structure from R11/R15 (passing). Concat-K over K=2048 (tiles 0..15:
// A=x,B=Wi; 16..31: A=h,B=Wh); r,z accumulate the sum; n-gate keeps i_n / h_n
// separate. Tile 128 rows x 32 gate-cols (96 reordered W rows), 4 waves (2x2).
// STAGE(t+1) ahead + one __syncthreads per tile; LDS dbuf 2x28KB, 2 blk/CU.
// L2-residency swizzle: per XCD 4 colTiles x 16 rowTiles (W set 768KB).
// R16: s_setprio hint pair removed (LDS-BW-bound lockstep: null-to-negative).
#define BUFSZ (224 * 64)   // (128 A-rows + 96 B-rows) * 64 k, elements
__global__ __launch_bounds__(256, 2)
void gru_fused(const unsigned short* __restrict__ x,   // [B,H] bf16 layer input
               const unsigned short* __restrict__ hb,  // [B,H] bf16 h_{t-1}
               const unsigned short* __restrict__ Wi,  // [3H,H] bf16 reordered
               const unsigned short* __restrict__ Wh,  // [3H,H] bf16 reordered
               const float* __restrict__ bih,          // [3H] original layout
               const float* __restrict__ bhh,          // [3H] original layout
               float* __restrict__ hout,               // [B,H] fp32 h'
               unsigned short* __restrict__ xout) {    // [B,H] bf16 h'
    const int bid = blockIdx.x;
    const int ii  = bid >> 3;               // 0..63 within XCD
    const int my  = ii & 15;                // row tile 0..15
    const int nxi = (bid & 7) * 4 + (ii >> 4);  // col tile 0..31

    __shared__ __align__(16) unsigned short lds[2 * BUFSZ];

    const int tid  = threadIdx.x;
    const int lane = tid & 63;
    const int w    = tid >> 6;
    const int wr   = w >> 1;         // wave row (0..1)
    const int wc   = w & 1;          // wave col / 16-col group (0..1)
    const long rowBase = (long)my * 128;
    const long colW    = (long)nxi * 96;   // reordered W row base

    f32x4 rz[4][2] = {};   // r,z gate sums (i+h), accumulated over all 32 steps
    f32x4 nin[4] = {};     // i_n (phase 0)
    f32x4 nhn[4] = {};     // h_n (phase 1)

    // ---- hoisted loop-invariant STAGE geometry (identical address values) ----
    long aoffE[4];                   // A-tile: global element offset per chunk i
    int  acb[4];                     // A-tile: LDS chunk base per i
    #pragma unroll
    for (int i = 0; i < 4; ++i) {
        const int cbase = (w * 4 + i) * 64;
        const int c = cbase + lane;
        const int r = c >> 3, jc = c & 7;
        const int js = (jc ^ (r & 7)) << 3;
        aoffE[i] = (rowBase + r) * (long)Hsz + js;
        acb[i]   = cbase;
    }
    long boffE[3];                   // B-tile
    int  bcb[3];
    #pragma unroll
    for (int i = 0; i < 3; ++i) {
        const int cbase = (w * 3 + i) * 64;
        const int c = cbase + lane;
        const int r = c >> 3, jc = c & 7;
        const int js = (jc ^ (r & 7)) << 3;
        boffE[i] = (colW + r) * (long)Hsz + js;
        bcb[i]   = cbase;
    }

    // Issue the 7 global_load_lds for K-tile tn into buffer buf.
    auto STAGE = [&](int tn, int buf) {
        const unsigned short* Ap = (tn < 16) ? x : hb;
        const unsigned short* Wp = (tn < 16) ? Wi : Wh;
        const long koff = (long)(tn & 15) * 64;
        unsigned short* la = lds + buf * BUFSZ;
        unsigned short* lb = la + 128 * 64;
        #pragma unroll
        for (int i = 0; i < 4; ++i)
            __builtin_amdgcn_global_load_lds((gvoid_t*)(Ap + aoffE[i] + koff),
                                             (svoid_t*)(la + acb[i] * 8), 16, 0, 0);
        #pragma unroll
        for (int i = 0; i < 3; ++i)
            __builtin_amdgcn_global_load_lds((gvoid_t*)(Wp + boffE[i] + koff),
                                             (svoid_t*)(lb + bcb[i] * 8), 16, 0, 0);
    };

    auto COMPUTE = [&](int t) {
        const unsigned short* la = lds + (t & 1) * BUFSZ;
        const unsigned short* lb = la + 128 * 64;
        const bool ph0 = (t < 16);               // wave-uniform
        #pragma unroll
        for (int kk = 0; kk < 2; ++kk) {
            s16x8 av[4], bv[3];
            const int jk = kk * 4 + (lane >> 4);
            #pragma unroll
            for (int mi = 0; mi < 4; ++mi) {
                int r = wr * 64 + mi * 16 + (lane & 15);
                av[mi] = *(const s16x8*)&la[r * 64 + ((jk ^ (r & 7)) << 3)];
            }
            #pragma unroll
            for (int ni = 0; ni < 3; ++ni) {
                int r = wc * 48 + ni * 16 + (lane & 15);
                bv[ni] = *(const s16x8*)&lb[r * 64 + ((jk ^ (r & 7)) << 3)];
            }
            #pragma unroll
            for (int mi = 0; mi < 4; ++mi) {
                mfma_bf16(rz[mi][0], av[mi], bv[0]);
                mfma_bf16(rz[mi][1], av[mi], bv[1]);
            }
            if (ph0) {
                #pragma unroll
                for (int mi = 0; mi < 4; ++mi) mfma_bf16(nin[mi], av[mi], bv[2]);
            } else {
                #pragma unroll
                for (int mi = 0; mi < 4; ++mi) mfma_bf16(nhn[mi], av[mi], bv[2]);
            }
        }
    };

    STAGE(0, 0);
    __syncthreads();                  // vmcnt(0) drain + barrier: tile 0 ready
    #pragma unroll
    for (int t = 0; t < 31; ++t) {
        STAGE(t + 1, (t + 1) & 1);    // overlaps with COMPUTE(t)
        COMPUTE(t);
        __syncthreads();              // drains t+1 loads; protects buf reuse
    }
    COMPUTE(31);

    // Guard MFMA-write -> VALU-read hazard (inline-asm MFMA bypasses the
    // compiler's hazard recognizer).
    asm volatile("s_nop 7\n\ts_nop 7");

    // ---- GRU epilogue (all per-lane, no cross-lane) ----
    const int j = nxi * 32 + wc * 16 + (lane & 15);   // gate column 0..1023
    const float br = bih[j]           + bhh[j];
    const float bz = bih[Hsz + j]     + bhh[Hsz + j];
    const float bin = bih[2 * Hsz + j];
    const float bhn = bhh[2 * Hsz + j];

    #pragma unroll
    for (int mi = 0; mi < 4; ++mi) {
        #pragma unroll
        for (int q = 0; q < 4; ++q) {
            long row = rowBase + wr * 64 + mi * 16 + ((lane >> 4) << 2) + q;
            float r = sigm(rz[mi][0][q] + br);
            float z = sigm(rz[mi][1][q] + bz);
            float n = tanh_fast(nin[mi][q] + bin + r * (nhn[mi][q] + bhn));
            float hv = bf2f(hb[row * Hsz + j]);   // bf16 hidden (L2-warm)
            float o  = (1.0f - z) * n + z * hv;
            hout[row * Hsz + j] = o;
            xout[row * Hsz + j] = f2bf(o);
        }
    }
}

// ---------------- decoder GEMM: C = A @ W^T + b (128x128 tile, m97 structure) ----------------
__global__ __launch_bounds__(256)
void gemm_dec(const unsigned short* __restrict__ A, const unsigned short* __restrict__ Bw,
              const float* __restrict__ bias, float* __restrict__ C,
              int M, int N, int K, int nx) {
    const int nwg = gridDim.x;
    const int cpx = nwg >> 3;
    const int bid = blockIdx.x;
    const int swz = (bid & 7) * cpx + (bid >> 3);
    const int my  = swz / nx;
    const int nxi = swz - my * nx;

    __shared__ __align__(16) unsigned short lA[128 * 64];
    __shared__ __align__(16) unsigned short lB[128 * 64];

    const int tid  = threadIdx.x;
    const int lane = tid & 63;
    const int w    = tid >> 6;
    const int wr   = w >> 1;
    const int wc   = w & 1;
    const long rowBase = (long)my * 128;
    const long colBase = (long)nxi * 128;

    f32x4 acc[4][4] = {};

    for (int k0 = 0; k0 < K; k0 += 64) {
        __syncthreads();
        #pragma unroll
        for (int i = 0; i < 4; ++i) {
            const int cbase = (w * 4 + i) * 64;
            const int c = cbase + lane;
            const int r = c >> 3, jc = c & 7;
            const int js = (jc ^ (r & 7)) << 3;
            __builtin_amdgcn_global_load_lds((gvoid_t*)(A  + (rowBase + r) * (long)K + k0 + js),
                                             (svoid_t*)(lA + cbase * 8), 16, 0, 0);
            __builtin_amdgcn_global_load_lds((gvoid_t*)(Bw + (colBase + r) * (long)K + k0 + js),
                                             (svoid_t*)(lB + cbase * 8), 16, 0, 0);
        }
        __syncthreads();

        #pragma unroll
        for (int kk = 0; kk < 2; ++kk) {
            s16x8 af[4], bf[4];
            const int jk = kk * 4 + (lane >> 4);
            #pragma unroll
            for (int mi = 0; mi < 4; ++mi) {
                int r = wr * 64 + mi * 16 + (lane & 15);
                af[mi] = *(const s16x8*)&lA[r * 64 + ((jk ^ (r & 7)) << 3)];
            }
            #pragma unroll
            for (int ni = 0; ni < 4; ++ni) {
                int r = wc * 64 + ni * 16 + (lane & 15);
                bf[ni] = *(const s16x8*)&lB[r * 64 + ((jk ^ (r & 7)) << 3)];
            }
            #pragma unroll
            for (int mi = 0; mi < 4; ++mi)
                #pragma unroll
                for (int ni = 0; ni < 4; ++ni)
                    mfma_bf16(acc[mi][ni], af[mi], bf[ni]);
        }
    }

    asm volatile("s_nop 7\n\ts_nop 7");

    #pragma unroll
    for (int mi = 0; mi < 4; ++mi) {
        #pragma unroll
        for (int ni = 0; ni < 4; ++ni) {
            long col = colBase + wc * 64 + ni * 16 + (lane & 15);
            float bv = bias[col];
            #pragma unroll
            for (int q = 0; q < 4; ++q) {
                long row = rowBase + wr * 64 + mi * 16 + (lane >> 4) * 4 + q;
                C[row * (long)N + col] = acc[mi][ni][q] + bv;
            }
        }
    }
}

extern "C" void kernel_launch(void* const* d_in, const int* in_sizes, int n_in,
                              void* d_out, int out_size, void* d_ws, size_t ws_size,
                              hipStream_t stream) {
    const float* input  = (const float*)d_in[0];
    const float* hidden = (const float*)d_in[1];
    const float* i2h_w  = (const float*)d_in[2];
    const float* i2h_b  = (const float*)d_in[3];
    const float* w_ih   = (const float*)d_in[4];
    const float* w_hh   = (const float*)d_in[5];
    const float* b_ih   = (const float*)d_in[6];
    const float* b_hh   = (const float*)d_in[7];
    const float* dec_w  = (const float*)d_in[8];
    const float* dec_b  = (const float*)d_in[9];

    float* logits = (float*)d_out;                       // [B, OUT]
    float* new_h  = (float*)d_out + (size_t)Bsz * OUTsz; // [L, B, H]

    // Workspace layout (~76 MB)
    char* p = (char*)d_ws;
    unsigned short* wih16  = (unsigned short*)p; p += (size_t)Lsz * 3 * Hsz * Hsz * 2;
    unsigned short* whh16  = (unsigned short*)p; p += (size_t)Lsz * 3 * Hsz * Hsz * 2;
    unsigned short* wdec16 = (unsigned short*)p; p += (size_t)OUTsz * Hsz * 2;
    unsigned short* h16    = (unsigned short*)p; p += (size_t)Lsz * Bsz * Hsz * 2;
    unsigned short* xb0    = (unsigned short*)p; p += (size_t)Bsz * Hsz * 2;
    unsigned short* xb1    = (unsigned short*)p; p += (size_t)Bsz * Hsz * 2;
    unsigned short* xbuf[2] = { xb0, xb1 };

    // 1) ALL pre-work in one grid-stride launch (G11: 4096 blocks)
    prework<<<4096, 256, 0, stream>>>(w_ih, wih16, w_hh, whh16,
                                      dec_w, wdec16, hidden, h16,
                                      input, i2h_w, i2h_b, xb0);

    // 2) fused GRU layers (one launch each; structure-frozen kernel)
    for (int l = 0; l < Lsz; ++l) {
        gru_fused<<<512, 256, 0, stream>>>(
            xbuf[l & 1],
            h16 + (size_t)l * Bsz * Hsz,
            wih16 + (size_t)l * 3 * Hsz * Hsz,
            whh16 + (size_t)l * 3 * Hsz * Hsz,
            b_ih + (size_t)l * 3 * Hsz,
            b_hh + (size_t)l * 3 * Hsz,
            new_h + (size_t)l * Bsz * Hsz,
            xbuf[(l + 1) & 1]);
    }

    // 3) decoder: logits = h3 @ dec_w.T + dec_b   (h3 is in xbuf[0] after 4 layers)
    {
        int nx = OUTsz / 128;                          // 2
        int blocks = nx * (Bsz / 128);                 // 32
        gemm_dec<<<blocks, 256, 0, stream>>>(xbuf[Lsz & 1], wdec16, dec_b, logits,
                                             Bsz, OUTsz, Hsz, nx);
    }
}